// Round 18
// baseline (69.858 us; speedup 1.0000x reference)
//
#include <hip/hip_runtime.h>
#include <hip/hip_bf16.h>
#include <math.h>

#define BB 2
#define LQ 4096
#define LKV 1024
#define QDIM 512
#define CDIM 768
#define HEADS 8
#define DHEAD 64
#define INNER 512
#define SCALE 0.125f

// exp(S*SCALE - 4) == exp2(S*C1 - C2)
#define C1 0.18033688011112042f
#define C2 5.7707801635558535f

typedef __bf16 bf16x4 __attribute__((ext_vector_type(4)));
typedef __bf16 bf16x8 __attribute__((ext_vector_type(8)));
typedef float f32x4 __attribute__((ext_vector_type(4)));

__device__ inline void gload16(const void* g, void* l) {
    __builtin_amdgcn_global_load_lds((const __attribute__((address_space(1))) unsigned int*)g,
                                     (__attribute__((address_space(3))) unsigned int*)l, 16, 0, 0);
}

// ---------------- weight prep: transpose+convert all 4 weights, tiled ----------------
__global__ __launch_bounds__(256)
void prep_weights(const float* __restrict__ Wq, const float* __restrict__ Wk,
                  const float* __restrict__ Wv, const float* __restrict__ Wo,
                  __bf16* __restrict__ Wq_t, __bf16* __restrict__ Wkv_t,
                  __bf16* __restrict__ Wo_t) {
    __shared__ float tile[32][33];
    int id = blockIdx.x;
    const float* W; __bf16* Out; int K;
    if (id < 256)       { W = Wq; Out = Wq_t; K = 512; }
    else if (id < 640)  { id -= 256;  W = Wk; Out = Wkv_t; K = 768; }
    else if (id < 1024) { id -= 640;  W = Wv; Out = Wkv_t + (size_t)512 * 768; K = 768; }
    else                { id -= 1024; W = Wo; Out = Wo_t; K = 512; }
    const int NT = 512 / 32;            // N==512 for all
    int kt = id / NT, nt = id % NT;
    const int t = threadIdx.x;
    int r = t >> 3, c4 = (t & 7) * 4;
    float4 v = *(const float4*)&W[(size_t)(kt * 32 + r) * 512 + nt * 32 + c4];
    tile[r][c4 + 0] = v.x; tile[r][c4 + 1] = v.y; tile[r][c4 + 2] = v.z; tile[r][c4 + 3] = v.w;
    __syncthreads();
    bf16x4 o = { (__bf16)tile[c4 + 0][r], (__bf16)tile[c4 + 1][r],
                 (__bf16)tile[c4 + 2][r], (__bf16)tile[c4 + 3][r] };
    *(bf16x4*)&Out[(size_t)(nt * 32 + r) * K + kt * 32 + c4] = o;
}

// ---------------- GEMM body (R17 datapath, dynamic LDS) ----------------
template<int BM, int BN, int BK, bool AF32, bool F32OUT, bool VTEP>
__device__ __forceinline__
void gemm_body(char* smem, int bx, int by, const void* __restrict__ Av,
               const __bf16* __restrict__ Bt, __bf16* __restrict__ Cb,
               float* __restrict__ Cf, const float* __restrict__ bias,
               __bf16* __restrict__ VT, int M, int N, int K, int CN) {
    static_assert(BK == 64, "swizzle assumes 128-byte rows");
    constexpr int WM = BM / 2, WN = BN / 2, FM = WM / 16, FN = WN / 16;
    constexpr int KK = BK / 32;
    constexpr int AQ4 = BM * BK / 1024;
    constexpr int AC8 = BM * BK / 2048;
    constexpr int BC8 = BN * BK / 2048;
    __bf16* As0 = (__bf16*)smem;                          // [2][BM*BK]
    __bf16* Bs0 = (__bf16*)(smem + (size_t)2 * BM * BK * 2);
    const int t = threadIdx.x;
    const int lane = t & 63;
    const int w = t >> 6;
    const int wm = w >> 1, wn = w & 1;
    const int bm = bx * BM, bn = by * BN;
    const float* Af = (const float*)Av;
    const __bf16* Ab = (const __bf16*)Av;
    f32x4 acc[FM][FN] = {};
    const int rr = lane & 15, kb8 = (lane >> 4) * 8;
    const int rsw = (rr & 7) << 4;
    const int NK = K / BK;

    float4 rA[AQ4];

    auto loadA = [&](int kt) {
        #pragma unroll
        for (int j = 0; j < AQ4; j++) {
            int q = t + 256 * j;
            rA[j] = *(const float4*)&Af[(size_t)(bm + (q >> 4)) * K + kt * BK + (q & 15) * 4];
        }
    };
    auto writeA = [&](int buf) {
        #pragma unroll
        for (int j = 0; j < AQ4; j++) {
            int q = t + 256 * j;
            bf16x4 o = { (__bf16)rA[j].x, (__bf16)rA[j].y, (__bf16)rA[j].z, (__bf16)rA[j].w };
            int row = q >> 4;
            *(bf16x4*)((char*)(As0 + buf * BM * BK) + ((q * 8) ^ ((row & 7) << 4))) = o;
        }
    };
    auto issueA = [&](int kt, int buf) {
        #pragma unroll
        for (int j = 0; j < AC8; j++) {
            int c = t + 256 * j;
            int row = c >> 3;
            int kc = (c & 7) ^ (row & 7);
            gload16(&Ab[(size_t)(bm + row) * K + kt * BK + kc * 8],
                    (char*)(As0 + buf * BM * BK) + (w * 64 + 256 * j) * 16);
        }
    };
    auto issueB = [&](int kt, int buf) {
        #pragma unroll
        for (int j = 0; j < BC8; j++) {
            int c = t + 256 * j;
            int row = c >> 3;
            int kc = (c & 7) ^ (row & 7);
            gload16(&Bt[(size_t)(bn + row) * K + kt * BK + kc * 8],
                    (char*)(Bs0 + buf * BN * BK) + (w * 64 + 256 * j) * 16);
        }
    };

    if (AF32) { loadA(0); writeA(0); if (NK > 1) loadA(1); }
    else issueA(0, 0);
    issueB(0, 0);
    __syncthreads();

    for (int kt = 0; kt < NK; kt++) {
        const int cur = kt & 1;
        if (kt + 1 < NK) {
            issueB(kt + 1, cur ^ 1);
            if (AF32) { writeA(cur ^ 1); if (kt + 2 < NK) loadA(kt + 2); }
            else issueA(kt + 1, cur ^ 1);
        }
        #pragma unroll
        for (int kk = 0; kk < KK; kk++) {
            bf16x8 a[FM], b[FN];
            #pragma unroll
            for (int f = 0; f < FM; f++)
                a[f] = *(const bf16x8*)((const char*)(As0 + cur * BM * BK) +
                    (((wm * WM + f * 16 + rr) * 128 + kk * 64 + kb8 * 2) ^ rsw));
            #pragma unroll
            for (int f = 0; f < FN; f++)
                b[f] = *(const bf16x8*)((const char*)(Bs0 + cur * BN * BK) +
                    (((wn * WN + f * 16 + rr) * 128 + kk * 64 + kb8 * 2) ^ rsw));
            __builtin_amdgcn_s_setprio(1);
            #pragma unroll
            for (int fm = 0; fm < FM; fm++)
                #pragma unroll
                for (int fn = 0; fn < FN; fn++)
                    acc[fm][fn] = __builtin_amdgcn_mfma_f32_16x16x32_bf16(a[fm], b[fn], acc[fm][fn], 0, 0, 0);
            __builtin_amdgcn_s_setprio(0);
        }
        __syncthreads();
    }

    const int colg = lane & 15;
    const int rowg = (lane >> 4) * 4;
    if (VTEP && bn >= 512) {
        __bf16* T = As0;
        #pragma unroll
        for (int fm = 0; fm < FM; fm++)
            #pragma unroll
            for (int fn = 0; fn < FN; fn++) {
                int dcol = wn * WN + fn * 16 + colg;
                int kvr  = wm * WM + fm * 16 + rowg;
                bf16x4 pv = { (__bf16)acc[fm][fn][0], (__bf16)acc[fm][fn][1],
                              (__bf16)acc[fm][fn][2], (__bf16)acc[fm][fn][3] };
                *(bf16x4*)((char*)T + ((dcol * 128 + kvr * 2) ^ ((dcol & 7) << 4))) = pv;
            }
        __syncthreads();
        int d = t >> 2, ch = t & 3;
        int base = d * 128 + ch * 32;
        bf16x8 o0 = *(const bf16x8*)((const char*)T + ((base) ^ ((d & 7) << 4)));
        bf16x8 o1 = *(const bf16x8*)((const char*)T + ((base + 16) ^ ((d & 7) << 4)));
        int b = bm >> 10, kv0 = bm & 1023, h = (bn - 512) >> 6;
        size_t vrow = (size_t)((b * 8 + h) * 64 + d);
        *(bf16x8*)&VT[vrow * 1024 + kv0 + ch * 16] = o0;
        *(bf16x8*)&VT[vrow * 1024 + kv0 + ch * 16 + 8] = o1;
    } else {
        #pragma unroll
        for (int fm = 0; fm < FM; fm++)
            #pragma unroll
            for (int fn = 0; fn < FN; fn++)
                #pragma unroll
                for (int r = 0; r < 4; r++) {
                    int row = bm + wm * WM + fm * 16 + rowg + r;
                    int col = bn + wn * WN + fn * 16 + colg;
                    float v = acc[fm][fn][r];
                    if (F32OUT) Cf[(size_t)row * CN + col] = v + bias[col];
                    else        Cb[(size_t)row * CN + col] = (__bf16)v;
                }
    }
}

// ---------------- fused Q-proj + KV-proj (independent GEMMs, one launch) ----------------
__global__ __launch_bounds__(256)
void proj_qkv(const float* __restrict__ hs, const __bf16* __restrict__ Wq_t, __bf16* __restrict__ Qb,
              const float* __restrict__ ehs, const __bf16* __restrict__ Wkv_t,
              __bf16* __restrict__ Kbb, __bf16* __restrict__ VTb) {
    extern __shared__ char smem[];
    int id = blockIdx.x;
    if (id < 512) {
        gemm_body<64, 128, 64, true, false, false>(smem, id & 127, id >> 7,
            hs, Wq_t, Qb, nullptr, nullptr, nullptr, BB * LQ, INNER, QDIM, INNER);
    } else {
        id -= 512;
        gemm_body<64, 64, 64, true, false, true>(smem, id & 31, id >> 5,
            ehs, Wkv_t, Kbb, nullptr, nullptr, VTb, BB * LKV, 1024, CDIM, INNER);
    }
}

// ---------------- O-projection ----------------
__global__ __launch_bounds__(256)
void proj_o(const __bf16* __restrict__ AOb, const __bf16* __restrict__ Wo_t,
            float* __restrict__ out, const float* __restrict__ bo) {
    extern __shared__ char smem[];
    gemm_body<64, 128, 64, false, true, false>(smem, blockIdx.x, blockIdx.y,
        AOb, Wo_t, nullptr, out, bo, nullptr, BB * LQ, QDIM, INNER, QDIM);
}

// ---------------- flash attention v12: attn11 minus Q LDS staging ----------------
__global__ __launch_bounds__(512, 2)
void attn12(const __bf16* __restrict__ Q, const __bf16* __restrict__ Kb,
            const __bf16* __restrict__ VT, __bf16* __restrict__ O) {
    __shared__ __align__(16) __bf16 SQ[128 * 64];         // per-wave P -> O bounce
    __shared__ __align__(16) __bf16 Ks[2][2][64 * 64];    // [dbuf][sub]
    __shared__ __align__(16) __bf16 Vs[2][2][64 * 64];
    const int t = threadIdx.x;
    const int lane = t & 63;
    const int w = t >> 6;               // 0..7, owns q rows w*16 .. w*16+15
    const int bh = blockIdx.y;
    const int b = bh >> 3, h = bh & 7;
    const int qbase = b * LQ + blockIdx.x * 128;
    const int kvbase = b * LKV;
    const int hq = h * 64;
    const int q16 = lane & 15;
    const int hh = lane >> 4;           // 0..3

    const int qrow = w * 16 + q16;
    const int rsw = (q16 & 7) << 4;

    // Q fragments direct from global (once; L2-hot from proj_qkv)
    bf16x8 qf0, qf1;
    {
        const __bf16* qp = &Q[(size_t)(qbase + qrow) * INNER + hq + hh * 8];
        qf0 = *(const bf16x8*)qp;
        qf1 = *(const bf16x8*)(qp + 32);
    }

    // K/V pair staging: thread covers row t>>3, 8 elems at (t&7)*8 in both subtiles
    const int srow = t >> 3;
    const int soff = ((srow * 128 + (t & 7) * 16) ^ ((srow & 7) << 4));
    bf16x8 kr[2], vr[2];
    auto loadPair = [&](int pt) {
        #pragma unroll
        for (int i = 0; i < 2; i++) {
            int tile = 2 * pt + i;
            kr[i] = *(const bf16x8*)&Kb[(size_t)(kvbase + tile * 64 + srow) * 512 + hq + (t & 7) * 8];
            vr[i] = *(const bf16x8*)&VT[((size_t)bh * 64 + srow) * 1024 + tile * 64 + (t & 7) * 8];
        }
    };
    auto writePair = [&](int buf) {
        #pragma unroll
        for (int i = 0; i < 2; i++) {
            *(bf16x8*)((char*)Ks[buf][i] + soff) = kr[i];
            *(bf16x8*)((char*)Vs[buf][i] + soff) = vr[i];
        }
    };

    loadPair(0);
    writePair(0);
    loadPair(1);
    __syncthreads();

    bf16x8 ones;
    #pragma unroll
    for (int j = 0; j < 8; j++) ones[j] = (__bf16)1.0f;

    f32x4 acc_o[4] = {};
    f32x4 acc_l = {};

    const int NP = LKV / 128;           // 8 pairs
    for (int pt = 0; pt < NP; pt++) {
        const int cur = pt & 1;
        if (pt > 0) __syncthreads();
        if (pt + 1 < NP) writePair(cur ^ 1);
        if (pt + 2 < NP) loadPair(pt + 2);

        #pragma unroll
        for (int sub = 0; sub < 2; sub++) {
            const char* Kbase = (const char*)Ks[cur][sub];
            const char* Vbase = (const char*)Vs[cur][sub];

            // S^T = K Q^T
            f32x4 s[4];
            __builtin_amdgcn_s_setprio(1);
            #pragma unroll
            for (int kvf = 0; kvf < 4; kvf++) {
                int krow = kvf * 16 + q16;
                bf16x8 k0 = *(const bf16x8*)(Kbase + ((krow * 128 + hh * 16) ^ rsw));
                bf16x8 k1 = *(const bf16x8*)(Kbase + ((krow * 128 + 64 + hh * 16) ^ rsw));
                f32x4 sa = {};
                sa = __builtin_amdgcn_mfma_f32_16x16x32_bf16(k0, qf0, sa, 0, 0, 0);
                sa = __builtin_amdgcn_mfma_f32_16x16x32_bf16(k1, qf1, sa, 0, 0, 0);
                s[kvf] = sa;
            }
            __builtin_amdgcn_s_setprio(0);

            // P = exp2(S*C1 - C2)
            #pragma unroll
            for (int kvf = 0; kvf < 4; kvf++) {
                bf16x4 pv;
                #pragma unroll
                for (int r = 0; r < 4; r++)
                    pv[r] = (__bf16)exp2f(__builtin_fmaf(s[kvf][r], C1, -C2));
                *(bf16x4*)((char*)SQ + ((qrow * 128 + kvf * 32 + hh * 8) ^ rsw)) = pv;
            }
            bf16x8 pa0 = *(const bf16x8*)((const char*)SQ + ((qrow * 128 + hh * 16) ^ rsw));
            bf16x8 pa1 = *(const bf16x8*)((const char*)SQ + ((qrow * 128 + 64 + hh * 16) ^ rsw));

            __builtin_amdgcn_s_setprio(1);
            acc_l = __builtin_amdgcn_mfma_f32_16x16x32_bf16(pa0, ones, acc_l, 0, 0, 0);
            acc_l = __builtin_amdgcn_mfma_f32_16x16x32_bf16(pa1, ones, acc_l, 0, 0, 0);
            #pragma unroll
            for (int df = 0; df < 4; df++) {
                int vrow = df * 16 + q16;
                bf16x8 v0 = *(const bf16x8*)(Vbase + ((vrow * 128 + hh * 16) ^ rsw));
                bf16x8 v1 = *(const bf16x8*)(Vbase + ((vrow * 128 + 64 + hh * 16) ^ rsw));
                acc_o[df] = __builtin_amdgcn_mfma_f32_16x16x32_bf16(pa0, v0, acc_o[df], 0, 0, 0);
                acc_o[df] = __builtin_amdgcn_mfma_f32_16x16x32_bf16(pa1, v1, acc_o[df], 0, 0, 0);
            }
            __builtin_amdgcn_s_setprio(0);
        }
    }

    // epilogue: normalize into own SQ rows, barrier, coalesced b128 out
    #pragma unroll
    for (int df = 0; df < 4; df++)
        #pragma unroll
        for (int r = 0; r < 4; r++) {
            float v = acc_o[df][r] / acc_l[r];
            int row = w * 16 + hh * 4 + r;
            int col = df * 16 + q16;
            *(__bf16*)((char*)SQ + ((row * 128 + col * 2) ^ ((row & 7) << 4))) = (__bf16)v;
        }
    __syncthreads();
    #pragma unroll
    for (int i = 0; i < 2; i++) {
        int c = t + 512 * i;
        int row = c >> 3;
        bf16x8 v = *(const bf16x8*)((const char*)SQ + ((row * 128 + (c & 7) * 16) ^ ((row & 7) << 4)));
        *(bf16x8*)&O[(size_t)(qbase + row) * INNER + hq + (c & 7) * 8] = v;
    }
}

extern "C" void kernel_launch(void* const* d_in, const int* in_sizes, int n_in,
                              void* d_out, int out_size, void* d_ws, size_t ws_size,
                              hipStream_t stream) {
    const float* hs  = (const float*)d_in[0];
    const float* ehs = (const float*)d_in[1];
    const float* Wq  = (const float*)d_in[2];
    const float* Wk  = (const float*)d_in[3];
    const float* Wv  = (const float*)d_in[4];
    const float* Wo  = (const float*)d_in[5];
    const float* bo  = (const float*)d_in[6];
    float* out = (float*)d_out;

    char* ws = (char*)d_ws;
    size_t off = 0;
    auto alloc = [&](size_t nbytes) {
        char* p = ws + off;
        off += (nbytes + 255) & ~(size_t)255;
        return p;
    };
    __bf16* Wq_t  = (__bf16*)alloc((size_t)QDIM * INNER * 2);
    __bf16* Wkv_t = (__bf16*)alloc((size_t)CDIM * INNER * 2 * 2);   // [1024][768]
    __bf16* Wo_t  = (__bf16*)alloc((size_t)INNER * QDIM * 2);
    __bf16* Qb    = (__bf16*)alloc((size_t)BB * LQ * INNER * 2);
    __bf16* Kbb   = (__bf16*)alloc((size_t)BB * LKV * INNER * 2);   // [2048][512]
    __bf16* VTb   = (__bf16*)alloc((size_t)BB * HEADS * DHEAD * LKV * 2);
    __bf16* AOb   = (__bf16*)alloc((size_t)BB * LQ * INNER * 2);

    prep_weights<<<dim3(1280), dim3(256), 0, stream>>>(Wq, Wk, Wv, Wo, Wq_t, Wkv_t, Wo_t);

    // fused: Q = hs @ Wq  and  [K|V] = ehs @ [Wk|Wv] (V transposed to VTb)
    proj_qkv<<<dim3(1024), dim3(256), 49152, stream>>>(hs, Wq_t, Qb, ehs, Wkv_t, Kbb, VTb);

    // attention
    attn12<<<dim3(LQ / 128, BB * HEADS), dim3(512), 0, stream>>>(Qb, Kbb, VTb, AOb);

    // out = AO @ Wo + bo  [8192, 512] f32
    proj_o<<<dim3(BB * LQ / 64, QDIM / 128), dim3(256), 49152, stream>>>(AOb, Wo_t, out, bo);
}

// Round 19
// 69.316 us; speedup vs baseline: 1.0078x; 1.0078x over previous
//
#include <hip/hip_runtime.h>
#include <hip/hip_bf16.h>
#include <math.h>

#define BB 2
#define LQ 4096
#define LKV 1024
#define QDIM 512
#define CDIM 768
#define HEADS 8
#define DHEAD 64
#define INNER 512
#define SCALE 0.125f

// exp(S*SCALE - 4) == exp2(S*C1 - C2)
#define C1 0.18033688011112042f
#define C2 5.7707801635558535f

typedef __bf16 bf16x4 __attribute__((ext_vector_type(4)));
typedef __bf16 bf16x8 __attribute__((ext_vector_type(8)));
typedef float f32x4 __attribute__((ext_vector_type(4)));

__device__ inline void gload16(const void* g, void* l) {
    __builtin_amdgcn_global_load_lds((const __attribute__((address_space(1))) unsigned int*)g,
                                     (__attribute__((address_space(3))) unsigned int*)l, 16, 0, 0);
}

// ---------------- transpose one 32x32 tile of a [K][512] f32 weight into [N][K] bf16 ----------------
__device__ __forceinline__
void wprep_tile(char* smem, int id, const float* __restrict__ W, __bf16* __restrict__ Out, int K) {
    float (*tile)[33] = (float(*)[33])smem;
    const int NT = 512 / 32;
    int kt = id / NT, nt = id % NT;
    const int t = threadIdx.x;
    int r = t >> 3, c4 = (t & 7) * 4;
    float4 v = *(const float4*)&W[(size_t)(kt * 32 + r) * 512 + nt * 32 + c4];
    tile[r][c4 + 0] = v.x; tile[r][c4 + 1] = v.y; tile[r][c4 + 2] = v.z; tile[r][c4 + 3] = v.w;
    __syncthreads();
    bf16x4 o = { (__bf16)tile[c4 + 0][r], (__bf16)tile[c4 + 1][r],
                 (__bf16)tile[c4 + 2][r], (__bf16)tile[c4 + 3][r] };
    *(bf16x4*)&Out[(size_t)(nt * 32 + r) * K + kt * 32 + c4] = o;
}

// ---------------- weight prep: Wq, Wk, Wv only (Wo handled inside proj_qkv) ----------------
__global__ __launch_bounds__(256)
void prep_weights(const float* __restrict__ Wq, const float* __restrict__ Wk,
                  const float* __restrict__ Wv, __bf16* __restrict__ Wq_t,
                  __bf16* __restrict__ Wkv_t) {
    __shared__ float tile[32][33];
    int id = blockIdx.x;
    if (id < 256)      wprep_tile((char*)tile, id, Wq, Wq_t, 512);
    else if (id < 640) wprep_tile((char*)tile, id - 256, Wk, Wkv_t, 768);
    else               wprep_tile((char*)tile, id - 640, Wv, Wkv_t + (size_t)512 * 768, 768);
}

// ---------------- GEMM body (R17 datapath, dynamic LDS) ----------------
template<int BM, int BN, int BK, bool AF32, bool F32OUT, bool VTEP>
__device__ __forceinline__
void gemm_body(char* smem, int bx, int by, const void* __restrict__ Av,
               const __bf16* __restrict__ Bt, __bf16* __restrict__ Cb,
               float* __restrict__ Cf, const float* __restrict__ bias,
               __bf16* __restrict__ VT, int M, int N, int K, int CN) {
    static_assert(BK == 64, "swizzle assumes 128-byte rows");
    constexpr int WM = BM / 2, WN = BN / 2, FM = WM / 16, FN = WN / 16;
    constexpr int KK = BK / 32;
    constexpr int AQ4 = BM * BK / 1024;
    constexpr int AC8 = BM * BK / 2048;
    constexpr int BC8 = BN * BK / 2048;
    __bf16* As0 = (__bf16*)smem;                          // [2][BM*BK]
    __bf16* Bs0 = (__bf16*)(smem + (size_t)2 * BM * BK * 2);
    const int t = threadIdx.x;
    const int lane = t & 63;
    const int w = t >> 6;
    const int wm = w >> 1, wn = w & 1;
    const int bm = bx * BM, bn = by * BN;
    const float* Af = (const float*)Av;
    const __bf16* Ab = (const __bf16*)Av;
    f32x4 acc[FM][FN] = {};
    const int rr = lane & 15, kb8 = (lane >> 4) * 8;
    const int rsw = (rr & 7) << 4;
    const int NK = K / BK;

    float4 rA[AQ4];

    auto loadA = [&](int kt) {
        #pragma unroll
        for (int j = 0; j < AQ4; j++) {
            int q = t + 256 * j;
            rA[j] = *(const float4*)&Af[(size_t)(bm + (q >> 4)) * K + kt * BK + (q & 15) * 4];
        }
    };
    auto writeA = [&](int buf) {
        #pragma unroll
        for (int j = 0; j < AQ4; j++) {
            int q = t + 256 * j;
            bf16x4 o = { (__bf16)rA[j].x, (__bf16)rA[j].y, (__bf16)rA[j].z, (__bf16)rA[j].w };
            int row = q >> 4;
            *(bf16x4*)((char*)(As0 + buf * BM * BK) + ((q * 8) ^ ((row & 7) << 4))) = o;
        }
    };
    auto issueA = [&](int kt, int buf) {
        #pragma unroll
        for (int j = 0; j < AC8; j++) {
            int c = t + 256 * j;
            int row = c >> 3;
            int kc = (c & 7) ^ (row & 7);
            gload16(&Ab[(size_t)(bm + row) * K + kt * BK + kc * 8],
                    (char*)(As0 + buf * BM * BK) + (w * 64 + 256 * j) * 16);
        }
    };
    auto issueB = [&](int kt, int buf) {
        #pragma unroll
        for (int j = 0; j < BC8; j++) {
            int c = t + 256 * j;
            int row = c >> 3;
            int kc = (c & 7) ^ (row & 7);
            gload16(&Bt[(size_t)(bn + row) * K + kt * BK + kc * 8],
                    (char*)(Bs0 + buf * BN * BK) + (w * 64 + 256 * j) * 16);
        }
    };

    if (AF32) { loadA(0); writeA(0); if (NK > 1) loadA(1); }
    else issueA(0, 0);
    issueB(0, 0);
    __syncthreads();

    for (int kt = 0; kt < NK; kt++) {
        const int cur = kt & 1;
        if (kt + 1 < NK) {
            issueB(kt + 1, cur ^ 1);
            if (AF32) { writeA(cur ^ 1); if (kt + 2 < NK) loadA(kt + 2); }
            else issueA(kt + 1, cur ^ 1);
        }
        #pragma unroll
        for (int kk = 0; kk < KK; kk++) {
            bf16x8 a[FM], b[FN];
            #pragma unroll
            for (int f = 0; f < FM; f++)
                a[f] = *(const bf16x8*)((const char*)(As0 + cur * BM * BK) +
                    (((wm * WM + f * 16 + rr) * 128 + kk * 64 + kb8 * 2) ^ rsw));
            #pragma unroll
            for (int f = 0; f < FN; f++)
                b[f] = *(const bf16x8*)((const char*)(Bs0 + cur * BN * BK) +
                    (((wn * WN + f * 16 + rr) * 128 + kk * 64 + kb8 * 2) ^ rsw));
            __builtin_amdgcn_s_setprio(1);
            #pragma unroll
            for (int fm = 0; fm < FM; fm++)
                #pragma unroll
                for (int fn = 0; fn < FN; fn++)
                    acc[fm][fn] = __builtin_amdgcn_mfma_f32_16x16x32_bf16(a[fm], b[fn], acc[fm][fn], 0, 0, 0);
            __builtin_amdgcn_s_setprio(0);
        }
        __syncthreads();
    }

    const int colg = lane & 15;
    const int rowg = (lane >> 4) * 4;
    if (VTEP && bn >= 512) {
        __bf16* T = As0;
        #pragma unroll
        for (int fm = 0; fm < FM; fm++)
            #pragma unroll
            for (int fn = 0; fn < FN; fn++) {
                int dcol = wn * WN + fn * 16 + colg;
                int kvr  = wm * WM + fm * 16 + rowg;
                bf16x4 pv = { (__bf16)acc[fm][fn][0], (__bf16)acc[fm][fn][1],
                              (__bf16)acc[fm][fn][2], (__bf16)acc[fm][fn][3] };
                *(bf16x4*)((char*)T + ((dcol * 128 + kvr * 2) ^ ((dcol & 7) << 4))) = pv;
            }
        __syncthreads();
        int d = t >> 2, ch = t & 3;
        int base = d * 128 + ch * 32;
        bf16x8 o0 = *(const bf16x8*)((const char*)T + ((base) ^ ((d & 7) << 4)));
        bf16x8 o1 = *(const bf16x8*)((const char*)T + ((base + 16) ^ ((d & 7) << 4)));
        int b = bm >> 10, kv0 = bm & 1023, h = (bn - 512) >> 6;
        size_t vrow = (size_t)((b * 8 + h) * 64 + d);
        *(bf16x8*)&VT[vrow * 1024 + kv0 + ch * 16] = o0;
        *(bf16x8*)&VT[vrow * 1024 + kv0 + ch * 16 + 8] = o1;
    } else {
        #pragma unroll
        for (int fm = 0; fm < FM; fm++)
            #pragma unroll
            for (int fn = 0; fn < FN; fn++)
                #pragma unroll
                for (int r = 0; r < 4; r++) {
                    int row = bm + wm * WM + fm * 16 + rowg + r;
                    int col = bn + wn * WN + fn * 16 + colg;
                    float v = acc[fm][fn][r];
                    if (F32OUT) Cf[(size_t)row * CN + col] = v + bias[col];
                    else        Cb[(size_t)row * CN + col] = (__bf16)v;
                }
    }
}

// ---------------- fused Q-proj + KV-proj + Wo-prep (one launch) ----------------
__global__ __launch_bounds__(256)
void proj_qkv(const float* __restrict__ hs, const __bf16* __restrict__ Wq_t, __bf16* __restrict__ Qb,
              const float* __restrict__ ehs, const __bf16* __restrict__ Wkv_t,
              __bf16* __restrict__ Kbb, __bf16* __restrict__ VTb,
              const float* __restrict__ Wo, __bf16* __restrict__ Wo_t) {
    extern __shared__ char smem[];
    int id = blockIdx.x;
    if (id < 512) {
        gemm_body<64, 128, 64, true, false, false>(smem, id & 127, id >> 7,
            hs, Wq_t, Qb, nullptr, nullptr, nullptr, BB * LQ, INNER, QDIM, INNER);
    } else if (id < 1024) {
        id -= 512;
        gemm_body<64, 64, 64, true, false, true>(smem, id & 31, id >> 5,
            ehs, Wkv_t, Kbb, nullptr, nullptr, VTb, BB * LKV, 1024, CDIM, INNER);
    } else {
        // Wo transpose (consumed only by proj_o, two launches later)
        wprep_tile(smem, id - 1024, Wo, Wo_t, 512);
    }
}

// ---------------- O-projection ----------------
__global__ __launch_bounds__(256)
void proj_o(const __bf16* __restrict__ AOb, const __bf16* __restrict__ Wo_t,
            float* __restrict__ out, const float* __restrict__ bo) {
    extern __shared__ char smem[];
    gemm_body<64, 128, 64, false, true, false>(smem, blockIdx.x, blockIdx.y,
        AOb, Wo_t, nullptr, out, bo, nullptr, BB * LQ, QDIM, INNER, QDIM);
}

// ---------------- flash attention v11 (R17 best): attn4 datapath, 2 KV tiles per barrier phase ----------------
__global__ __launch_bounds__(512, 2)
void attn11(const __bf16* __restrict__ Q, const __bf16* __restrict__ Kb,
            const __bf16* __restrict__ VT, __bf16* __restrict__ O) {
    __shared__ __align__(16) __bf16 SQ[128 * 64];         // Q stage -> per-wave P -> O bounce
    __shared__ __align__(16) __bf16 Ks[2][2][64 * 64];    // [dbuf][sub]
    __shared__ __align__(16) __bf16 Vs[2][2][64 * 64];
    const int t = threadIdx.x;
    const int lane = t & 63;
    const int w = t >> 6;               // 0..7, owns q rows w*16 .. w*16+15
    const int bh = blockIdx.y;
    const int b = bh >> 3, h = bh & 7;
    const int qbase = b * LQ + blockIdx.x * 128;
    const int kvbase = b * LKV;
    const int hq = h * 64;
    const int q16 = lane & 15;
    const int hh = lane >> 4;           // 0..3

    // stage Q tile (128 x 64), swizzled
    #pragma unroll
    for (int i = 0; i < 2; i++) {
        int c = t + 512 * i;
        int row = c >> 3;
        bf16x8 v = *(const bf16x8*)&Q[(size_t)(qbase + row) * INNER + hq + (c & 7) * 8];
        *(bf16x8*)((char*)SQ + ((row * 128 + (c & 7) * 16) ^ ((row & 7) << 4))) = v;
    }

    // K/V pair staging: thread covers row t>>3, 8 elems at (t&7)*8 in both subtiles
    const int srow = t >> 3;
    const int soff = ((srow * 128 + (t & 7) * 16) ^ ((srow & 7) << 4));
    bf16x8 kr[2], vr[2];
    auto loadPair = [&](int pt) {
        #pragma unroll
        for (int i = 0; i < 2; i++) {
            int tile = 2 * pt + i;
            kr[i] = *(const bf16x8*)&Kb[(size_t)(kvbase + tile * 64 + srow) * 512 + hq + (t & 7) * 8];
            vr[i] = *(const bf16x8*)&VT[((size_t)bh * 64 + srow) * 1024 + tile * 64 + (t & 7) * 8];
        }
    };
    auto writePair = [&](int buf) {
        #pragma unroll
        for (int i = 0; i < 2; i++) {
            *(bf16x8*)((char*)Ks[buf][i] + soff) = kr[i];
            *(bf16x8*)((char*)Vs[buf][i] + soff) = vr[i];
        }
    };

    loadPair(0);
    writePair(0);
    loadPair(1);
    __syncthreads();

    const int qrow = w * 16 + q16;
    const int rsw = (q16 & 7) << 4;
    bf16x8 qf0 = *(const bf16x8*)((const char*)SQ + ((qrow * 128 + hh * 16) ^ rsw));
    bf16x8 qf1 = *(const bf16x8*)((const char*)SQ + ((qrow * 128 + 64 + hh * 16) ^ rsw));
    bf16x8 ones;
    #pragma unroll
    for (int j = 0; j < 8; j++) ones[j] = (__bf16)1.0f;

    f32x4 acc_o[4] = {};
    f32x4 acc_l = {};

    const int NP = LKV / 128;           // 8 pairs
    for (int pt = 0; pt < NP; pt++) {
        const int cur = pt & 1;
        if (pt > 0) __syncthreads();
        if (pt + 1 < NP) writePair(cur ^ 1);
        if (pt + 2 < NP) loadPair(pt + 2);

        #pragma unroll
        for (int sub = 0; sub < 2; sub++) {
            const char* Kbase = (const char*)Ks[cur][sub];
            const char* Vbase = (const char*)Vs[cur][sub];

            // S^T = K Q^T
            f32x4 s[4];
            __builtin_amdgcn_s_setprio(1);
            #pragma unroll
            for (int kvf = 0; kvf < 4; kvf++) {
                int krow = kvf * 16 + q16;
                bf16x8 k0 = *(const bf16x8*)(Kbase + ((krow * 128 + hh * 16) ^ rsw));
                bf16x8 k1 = *(const bf16x8*)(Kbase + ((krow * 128 + 64 + hh * 16) ^ rsw));
                f32x4 sa = {};
                sa = __builtin_amdgcn_mfma_f32_16x16x32_bf16(k0, qf0, sa, 0, 0, 0);
                sa = __builtin_amdgcn_mfma_f32_16x16x32_bf16(k1, qf1, sa, 0, 0, 0);
                s[kvf] = sa;
            }
            __builtin_amdgcn_s_setprio(0);

            // P = exp2(S*C1 - C2)
            #pragma unroll
            for (int kvf = 0; kvf < 4; kvf++) {
                bf16x4 pv;
                #pragma unroll
                for (int r = 0; r < 4; r++)
                    pv[r] = (__bf16)exp2f(__builtin_fmaf(s[kvf][r], C1, -C2));
                *(bf16x4*)((char*)SQ + ((qrow * 128 + kvf * 32 + hh * 8) ^ rsw)) = pv;
            }
            bf16x8 pa0 = *(const bf16x8*)((const char*)SQ + ((qrow * 128 + hh * 16) ^ rsw));
            bf16x8 pa1 = *(const bf16x8*)((const char*)SQ + ((qrow * 128 + 64 + hh * 16) ^ rsw));

            __builtin_amdgcn_s_setprio(1);
            acc_l = __builtin_amdgcn_mfma_f32_16x16x32_bf16(pa0, ones, acc_l, 0, 0, 0);
            acc_l = __builtin_amdgcn_mfma_f32_16x16x32_bf16(pa1, ones, acc_l, 0, 0, 0);
            #pragma unroll
            for (int df = 0; df < 4; df++) {
                int vrow = df * 16 + q16;
                bf16x8 v0 = *(const bf16x8*)(Vbase + ((vrow * 128 + hh * 16) ^ rsw));
                bf16x8 v1 = *(const bf16x8*)(Vbase + ((vrow * 128 + 64 + hh * 16) ^ rsw));
                acc_o[df] = __builtin_amdgcn_mfma_f32_16x16x32_bf16(pa0, v0, acc_o[df], 0, 0, 0);
                acc_o[df] = __builtin_amdgcn_mfma_f32_16x16x32_bf16(pa1, v1, acc_o[df], 0, 0, 0);
            }
            __builtin_amdgcn_s_setprio(0);
        }
    }

    // epilogue: normalize into own SQ rows, barrier, coalesced b128 out
    #pragma unroll
    for (int df = 0; df < 4; df++)
        #pragma unroll
        for (int r = 0; r < 4; r++) {
            float v = acc_o[df][r] / acc_l[r];
            int row = w * 16 + hh * 4 + r;
            int col = df * 16 + q16;
            *(__bf16*)((char*)SQ + ((row * 128 + col * 2) ^ ((row & 7) << 4))) = (__bf16)v;
        }
    __syncthreads();
    #pragma unroll
    for (int i = 0; i < 2; i++) {
        int c = t + 512 * i;
        int row = c >> 3;
        bf16x8 v = *(const bf16x8*)((const char*)SQ + ((row * 128 + (c & 7) * 16) ^ ((row & 7) << 4)));
        *(bf16x8*)&O[(size_t)(qbase + row) * INNER + hq + (c & 7) * 8] = v;
    }
}

extern "C" void kernel_launch(void* const* d_in, const int* in_sizes, int n_in,
                              void* d_out, int out_size, void* d_ws, size_t ws_size,
                              hipStream_t stream) {
    const float* hs  = (const float*)d_in[0];
    const float* ehs = (const float*)d_in[1];
    const float* Wq  = (const float*)d_in[2];
    const float* Wk  = (const float*)d_in[3];
    const float* Wv  = (const float*)d_in[4];
    const float* Wo  = (const float*)d_in[5];
    const float* bo  = (const float*)d_in[6];
    float* out = (float*)d_out;

    char* ws = (char*)d_ws;
    size_t off = 0;
    auto alloc = [&](size_t nbytes) {
        char* p = ws + off;
        off += (nbytes + 255) & ~(size_t)255;
        return p;
    };
    __bf16* Wq_t  = (__bf16*)alloc((size_t)QDIM * INNER * 2);
    __bf16* Wkv_t = (__bf16*)alloc((size_t)CDIM * INNER * 2 * 2);   // [1024][768]
    __bf16* Wo_t  = (__bf16*)alloc((size_t)INNER * QDIM * 2);
    __bf16* Qb    = (__bf16*)alloc((size_t)BB * LQ * INNER * 2);
    __bf16* Kbb   = (__bf16*)alloc((size_t)BB * LKV * INNER * 2);   // [2048][512]
    __bf16* VTb   = (__bf16*)alloc((size_t)BB * HEADS * DHEAD * LKV * 2);
    __bf16* AOb   = (__bf16*)alloc((size_t)BB * LQ * INNER * 2);

    // prep Wq, Wk, Wv (Wo folded into proj_qkv)
    prep_weights<<<dim3(1024), dim3(256), 0, stream>>>(Wq, Wk, Wv, Wq_t, Wkv_t);

    // fused: Q = hs @ Wq, [K|V] = ehs @ [Wk|Wv] (V transposed), + Wo transpose
    proj_qkv<<<dim3(1280), dim3(256), 49152, stream>>>(hs, Wq_t, Qb, ehs, Wkv_t, Kbb, VTb, Wo, Wo_t);

    // attention
    attn11<<<dim3(LQ / 128, BB * HEADS), dim3(512), 0, stream>>>(Qb, Kbb, VTb, AOb);

    // out = AO @ Wo + bo  [8192, 512] f32
    proj_o<<<dim3(BB * LQ / 64, QDIM / 128), dim3(256), 49152, stream>>>(AOb, Wo_t, out, bo);
}